// Round 3
// baseline (514.908 us; speedup 1.0000x reference)
//
#include <hip/hip_runtime.h>
#include <cstdint>
#include <cstddef>

typedef __attribute__((ext_vector_type(8))) short short8;
typedef __attribute__((ext_vector_type(4))) float f32x4;

#define D_FEAT 512
#define D_HID  1024
#define NCOL   2048   // UV columns = 2*D_HID (U | V)
#define NBUCK  1024   // src buckets (s>>6), covers N_NODES<=65536

__device__ __forceinline__ unsigned short f2bf(float f) {
    unsigned u = __builtin_bit_cast(unsigned, f);
    u += 0x7FFFu + ((u >> 16) & 1u);   // round-to-nearest-even
    return (unsigned short)(u >> 16);
}
__device__ __forceinline__ float bf2f(unsigned short h) {
    unsigned u = ((unsigned)h) << 16;
    return __builtin_bit_cast(float, u);
}

// ---------- kernel 1: x fp32 -> bf16 ----------
__global__ __launch_bounds__(256) void cast_x_kernel(const float* __restrict__ x,
                                                     unsigned short* __restrict__ xb,
                                                     int n) {
    int i = (blockIdx.x * 256 + threadIdx.x) * 8;
    if (i >= n) return;
    const float4* xp = (const float4*)(x + i);
    float4 a = xp[0], b = xp[1];
    short8 o;
    o[0] = (short)f2bf(a.x); o[1] = (short)f2bf(a.y);
    o[2] = (short)f2bf(a.z); o[3] = (short)f2bf(a.w);
    o[4] = (short)f2bf(b.x); o[5] = (short)f2bf(b.y);
    o[6] = (short)f2bf(b.z); o[7] = (short)f2bf(b.w);
    *(short8*)(xb + i) = o;
}

// ---------- kernel 2: W1 [1024][1024] fp32 -> w1t bf16 [2048][512] (B^T, U|V stacked) ----------
__global__ __launch_bounds__(256) void transpose_w1_kernel(const float* __restrict__ W1,
                                                           unsigned short* __restrict__ w1t) {
    __shared__ float tile[32][33];
    const int half = blockIdx.z;
    const int kb = blockIdx.y * 32;
    const int nb = blockIdx.x * 32;
    const int tx = threadIdx.x, ty = threadIdx.y;
    #pragma unroll
    for (int i = 0; i < 32; i += 8)
        tile[ty + i][tx] = W1[(size_t)(half * 512 + kb + ty + i) * 1024 + nb + tx];
    __syncthreads();
    #pragma unroll
    for (int i = 0; i < 32; i += 8)
        w1t[(size_t)(half * 1024 + nb + ty + i) * 512 + kb + tx] = f2bf(tile[tx][ty + i]);
}

// ---------- kernel 3: UV = xb @ w1t^T  (M=50000, K=512, N=2048), +b1 on U half, bf16 out ----------
// XOR-swizzled LDS (granule p = cg ^ (row&7)) -> staging stays wave-uniform+lane*16B
// (global_load_lds constraint) while read-side hits 8 distinct bank clusters (2-way, free).
#define BM 128
#define BN 128
#define BK 64

__global__ __launch_bounds__(256, 2) void gemm_uv_kernel(
    const unsigned short* __restrict__ xb,
    const unsigned short* __restrict__ w1t,
    const float* __restrict__ b1,
    unsigned short* __restrict__ UV,
    int M)
{
    __shared__ __align__(16) unsigned short smem[20480];
    unsigned short* sA = smem;
    unsigned short* sB = smem + 8192;

    const int tid  = threadIdx.x;
    const int wave = tid >> 6;
    const int lane = tid & 63;
    const int q    = lane >> 4;
    const int l15  = lane & 15;
    const int wm   = (wave >> 1) * 64;
    const int wn   = (wave & 1) * 64;
    const int m0   = blockIdx.x * BM;
    const int n0   = blockIdx.y * BN;

    const int ar = lane >> 3;
    const int ac = ((lane & 7) ^ ar) * 8;       // swizzled staging col-group

    const int swz = l15 & 7;
    const int c0 = (q ^ swz) * 8;               // ks = 0
    const int c1 = ((q ^ swz) ^ 4) * 8;         // ks = 32

    f32x4 zero = {0.f, 0.f, 0.f, 0.f};
    f32x4 acc[4][4];
    #pragma unroll
    for (int i = 0; i < 4; ++i)
        #pragma unroll
        for (int j = 0; j < 4; ++j)
            acc[i][j] = zero;

    #pragma unroll 1
    for (int kt = 0; kt < 8; ++kt) {
        const int k0 = kt * BK;
        __syncthreads();
        #pragma unroll
        for (int i = 0; i < 4; ++i) {
            int slot = wave * 4 + i;
            int row  = slot * 8 + ar;
            int m    = m0 + row; if (m >= M) m = M - 1;
            __builtin_amdgcn_global_load_lds(
                (const __attribute__((address_space(1))) void*)(xb + (size_t)m * D_FEAT + k0 + ac),
                (__attribute__((address_space(3))) void*)(sA + slot * 512),
                16, 0, 0);
        }
        #pragma unroll
        for (int i = 0; i < 4; ++i) {
            int slot = wave * 4 + i;
            int row  = slot * 8 + ar;
            __builtin_amdgcn_global_load_lds(
                (const __attribute__((address_space(1))) void*)(w1t + (size_t)(n0 + row) * D_FEAT + k0 + ac),
                (__attribute__((address_space(3))) void*)(sB + slot * 512),
                16, 0, 0);
        }
        __syncthreads();
        {
            short8 a[4], b[4];
            #pragma unroll
            for (int mt = 0; mt < 4; ++mt)
                a[mt] = *(const short8*)(sA + (wm + mt * 16 + l15) * 64 + c0);
            #pragma unroll
            for (int nt = 0; nt < 4; ++nt)
                b[nt] = *(const short8*)(sB + (wn + nt * 16 + l15) * 64 + c0);
            #pragma unroll
            for (int mt = 0; mt < 4; ++mt)
                #pragma unroll
                for (int nt = 0; nt < 4; ++nt)
                    acc[mt][nt] = __builtin_amdgcn_mfma_f32_16x16x32_bf16(a[mt], b[nt], acc[mt][nt], 0, 0, 0);
            #pragma unroll
            for (int mt = 0; mt < 4; ++mt)
                a[mt] = *(const short8*)(sA + (wm + mt * 16 + l15) * 64 + c1);
            #pragma unroll
            for (int nt = 0; nt < 4; ++nt)
                b[nt] = *(const short8*)(sB + (wn + nt * 16 + l15) * 64 + c1);
            #pragma unroll
            for (int mt = 0; mt < 4; ++mt)
                #pragma unroll
                for (int nt = 0; nt < 4; ++nt)
                    acc[mt][nt] = __builtin_amdgcn_mfma_f32_16x16x32_bf16(a[mt], b[nt], acc[mt][nt], 0, 0, 0);
        }
    }

    float b1v[4];
    #pragma unroll
    for (int nt = 0; nt < 4; ++nt) {
        int n = n0 + wn + nt * 16 + l15;
        b1v[nt] = (n < D_HID) ? b1[n] : 0.f;
    }
    __syncthreads();
    unsigned short* ep = smem + wave * 5120;   // wave-private [64][80]
    #pragma unroll
    for (int mt = 0; mt < 4; ++mt)
        #pragma unroll
        for (int nt = 0; nt < 4; ++nt)
            #pragma unroll
            for (int r = 0; r < 4; ++r) {
                float v = acc[mt][nt][r] + b1v[nt];
                ep[(mt * 16 + q * 4 + r) * 80 + nt * 16 + l15] = f2bf(v);
            }
    __syncthreads();
    #pragma unroll
    for (int i = 0; i < 8; ++i) {
        int flat = i * 64 + lane;
        int r  = flat >> 3;
        int c8 = (flat & 7) * 8;
        int m  = m0 + wm + r;
        if (m < M) {
            short8 v = *(const short8*)(ep + r * 80 + c8);
            *(short8*)(UV + (size_t)m * NCOL + n0 + wn + c8) = v;
        }
    }
}

// ---------- edge bucketing: counting sort by src>>6 for U-row L2 locality ----------
__global__ __launch_bounds__(1024) void zero_hist_kernel(int* __restrict__ hist) {
    hist[threadIdx.x] = 0;
}

__global__ __launch_bounds__(256) void hist_kernel(const int* __restrict__ src,
                                                   int* __restrict__ hist, int E) {
    int e = blockIdx.x * 256 + threadIdx.x;
    if (e < E) atomicAdd(&hist[src[e] >> 6], 1);
}

__global__ __launch_bounds__(1024) void scan_kernel(const int* __restrict__ hist,
                                                    int* __restrict__ off) {
    __shared__ int tmp[NBUCK];
    int t = threadIdx.x;
    int v = hist[t];
    tmp[t] = v;
    __syncthreads();
    #pragma unroll
    for (int d = 1; d < NBUCK; d <<= 1) {
        int add = (t >= d) ? tmp[t - d] : 0;
        __syncthreads();
        tmp[t] += add;
        __syncthreads();
    }
    off[t] = tmp[t] - v;   // exclusive prefix
}

__global__ __launch_bounds__(256) void scatter_kernel(const int* __restrict__ src,
                                                      int* __restrict__ off,
                                                      int* __restrict__ perm, int E) {
    int e = blockIdx.x * 256 + threadIdx.x;
    if (e < E) {
        int pos = atomicAdd(&off[src[e] >> 6], 1);
        perm[pos] = e;
    }
}

// ---------- kernel 4: per-edge score = relu(U[s]+V[d]) . W2 + b2, bucket-ordered ----------
__global__ __launch_bounds__(256) void edge_score_kernel(
    const unsigned short* __restrict__ UV,
    const int* __restrict__ perm,
    const int* __restrict__ src, const int* __restrict__ dst,
    const float* __restrict__ W2, const float* __restrict__ b2,
    float* __restrict__ out, int E)
{
    const int wave = threadIdx.x >> 6;
    const int lane = threadIdx.x & 63;
    const int i = blockIdx.x * 4 + wave;
    if (i >= E) return;
    const int e = perm[i];
    const int s = src[e];
    const int d = dst[e];
    const unsigned short* up = UV + (size_t)s * NCOL + lane * 16;
    const unsigned short* vp = UV + (size_t)d * NCOL + D_HID + lane * 16;
    short8 u0 = *(const short8*)up;
    short8 u1 = *(const short8*)(up + 8);
    short8 v0 = *(const short8*)vp;
    short8 v1 = *(const short8*)(vp + 8);
    const float4* wp = (const float4*)(W2 + lane * 16);
    float4 wa = wp[0], wb = wp[1], wc = wp[2], wd = wp[3];
    float w[16] = {wa.x, wa.y, wa.z, wa.w, wb.x, wb.y, wb.z, wb.w,
                   wc.x, wc.y, wc.z, wc.w, wd.x, wd.y, wd.z, wd.w};
    float acc = 0.f;
    #pragma unroll
    for (int k = 0; k < 8; ++k) {
        float h = bf2f((unsigned short)u0[k]) + bf2f((unsigned short)v0[k]);
        acc = fmaf(fmaxf(h, 0.f), w[k], acc);
    }
    #pragma unroll
    for (int k = 0; k < 8; ++k) {
        float h = bf2f((unsigned short)u1[k]) + bf2f((unsigned short)v1[k]);
        acc = fmaf(fmaxf(h, 0.f), w[8 + k], acc);
    }
    #pragma unroll
    for (int off = 1; off < 64; off <<= 1)
        acc += __shfl_xor(acc, off);
    if (lane == 0) out[e] = acc + b2[0];
}

extern "C" void kernel_launch(void* const* d_in, const int* in_sizes, int n_in,
                              void* d_out, int out_size, void* d_ws, size_t ws_size,
                              hipStream_t stream) {
    const float* x   = (const float*)d_in[0];
    const int*   src = (const int*)d_in[1];
    const int*   dst = (const int*)d_in[2];
    const float* W1  = (const float*)d_in[3];
    const float* b1  = (const float*)d_in[4];
    const float* W2  = (const float*)d_in[5];
    const float* b2  = (const float*)d_in[6];
    float* out = (float*)d_out;

    const int M = in_sizes[0] / D_FEAT;   // 50000 nodes
    const int E = in_sizes[1];            // 200000 edges

    // workspace: UV bf16 [M][2048] | xb bf16 [M][512] | w1t bf16 [2048][512]
    //          | hist[1024] | off[1024] | perm[E]
    char* ws = (char*)d_ws;
    unsigned short* UV  = (unsigned short*)ws;
    unsigned short* xb  = (unsigned short*)(ws + (size_t)M * NCOL * 2);
    unsigned short* w1t = (unsigned short*)(ws + (size_t)M * NCOL * 2 + (size_t)M * D_FEAT * 2);
    char* p = ws + (size_t)M * NCOL * 2 + (size_t)M * D_FEAT * 2 + (size_t)NCOL * D_FEAT * 2;
    int* hist = (int*)p;
    int* off  = (int*)(p + NBUCK * 4);
    int* perm = (int*)(p + 2 * NBUCK * 4);

    const int nx = M * D_FEAT;
    // edge bucketing (independent of x/W1 path; all tiny)
    zero_hist_kernel<<<1, NBUCK, 0, stream>>>(hist);
    hist_kernel<<<(E + 255) / 256, 256, 0, stream>>>(src, hist, E);
    scan_kernel<<<1, NBUCK, 0, stream>>>(hist, off);
    scatter_kernel<<<(E + 255) / 256, 256, 0, stream>>>(src, off, perm, E);

    cast_x_kernel<<<(nx / 8 + 255) / 256, 256, 0, stream>>>(x, xb, nx);
    transpose_w1_kernel<<<dim3(32, 16, 2), dim3(32, 8), 0, stream>>>(W1, w1t);
    gemm_uv_kernel<<<dim3((M + BM - 1) / BM, NCOL / BN), 256, 0, stream>>>(xb, w1t, b1, UV, M);
    edge_score_kernel<<<(E + 3) / 4, 256, 0, stream>>>(UV, perm, src, dst, W2, b2, out, E);
}

// Round 4
// 481.930 us; speedup vs baseline: 1.0684x; 1.0684x over previous
//
#include <hip/hip_runtime.h>
#include <cstdint>
#include <cstddef>

typedef __attribute__((ext_vector_type(8))) short short8;
typedef __attribute__((ext_vector_type(4))) float f32x4;

#define D_FEAT 512
#define D_HID  1024
#define NCOL   2048   // UV columns = 2*D_HID (U | V)

__device__ __forceinline__ unsigned short f2bf(float f) {
    unsigned u = __builtin_bit_cast(unsigned, f);
    u += 0x7FFFu + ((u >> 16) & 1u);   // round-to-nearest-even
    return (unsigned short)(u >> 16);
}
__device__ __forceinline__ float bf2f(unsigned short h) {
    unsigned u = ((unsigned)h) << 16;
    return __builtin_bit_cast(float, u);
}

// ---------- kernel 1: x fp32 -> bf16 ----------
__global__ __launch_bounds__(256) void cast_x_kernel(const float* __restrict__ x,
                                                     unsigned short* __restrict__ xb,
                                                     int n) {
    int i = (blockIdx.x * 256 + threadIdx.x) * 8;
    if (i >= n) return;
    const float4* xp = (const float4*)(x + i);
    float4 a = xp[0], b = xp[1];
    short8 o;
    o[0] = (short)f2bf(a.x); o[1] = (short)f2bf(a.y);
    o[2] = (short)f2bf(a.z); o[3] = (short)f2bf(a.w);
    o[4] = (short)f2bf(b.x); o[5] = (short)f2bf(b.y);
    o[6] = (short)f2bf(b.z); o[7] = (short)f2bf(b.w);
    *(short8*)(xb + i) = o;
}

// ---------- kernel 2: W1 [1024][1024] fp32 -> w1t bf16 [2048][512] (B^T, U|V stacked) ----------
__global__ __launch_bounds__(256) void transpose_w1_kernel(const float* __restrict__ W1,
                                                           unsigned short* __restrict__ w1t) {
    __shared__ float tile[32][33];
    const int half = blockIdx.z;
    const int kb = blockIdx.y * 32;
    const int nb = blockIdx.x * 32;
    const int tx = threadIdx.x, ty = threadIdx.y;
    #pragma unroll
    for (int i = 0; i < 32; i += 8)
        tile[ty + i][tx] = W1[(size_t)(half * 512 + kb + ty + i) * 1024 + nb + tx];
    __syncthreads();
    #pragma unroll
    for (int i = 0; i < 32; i += 8)
        w1t[(size_t)(half * 1024 + nb + ty + i) * 512 + kb + tx] = f2bf(tile[tx][ty + i]);
}

// ---------- kernel 3: UV = xb @ w1t^T  (M=50000, K=512, N=2048), +b1 on U half, bf16 out ----------
// XOR-swizzled LDS (granule p = cg ^ (row&7)): staging stays wave-uniform+lane*16B
// (global_load_lds constraint) while read-side hits 8 distinct bank clusters (2-way, free).
// Grid is 1D, swizzled into supergroups of GM m-blocks x all n-blocks so the
// ~512-block co-residency window shares one A panel (FETCH ~ A once + B once).
#define BM 128
#define BN 128
#define BK 64
#define GM 32   // m-blocks per supergroup; GM*NB = 512 blocks ~ one residency window

__global__ __launch_bounds__(256, 5) void gemm_uv_kernel(
    const unsigned short* __restrict__ xb,
    const unsigned short* __restrict__ w1t,
    const float* __restrict__ b1,
    unsigned short* __restrict__ UV,
    int M, int MB)   // MB = number of m-blocks
{
    // staging sA+sB = 32 KB; epilogue reuses the same 32 KB (4 waves x [64][64] shorts)
    __shared__ __align__(16) unsigned short smem[16384];
    unsigned short* sA = smem;
    unsigned short* sB = smem + 8192;

    const int NB = NCOL / BN;   // 16
    int bid = blockIdx.x;
    int g    = bid / (GM * NB);
    int rem  = bid - g * (GM * NB);
    int base = g * GM;
    int gm   = MB - base; if (gm > GM) gm = GM;
    int mb   = base + rem % gm;
    int nb   = rem / gm;
    const int m0 = mb * BM;
    const int n0 = nb * BN;

    const int tid  = threadIdx.x;
    const int wave = tid >> 6;
    const int lane = tid & 63;
    const int q    = lane >> 4;
    const int l15  = lane & 15;
    const int wm   = (wave >> 1) * 64;
    const int wn   = (wave & 1) * 64;

    const int ar = lane >> 3;
    const int ac = ((lane & 7) ^ ar) * 8;       // swizzled staging col-group

    const int swz = l15 & 7;
    const int c0 = (q ^ swz) * 8;               // ks = 0
    const int c1 = ((q ^ swz) ^ 4) * 8;         // ks = 32

    f32x4 zero = {0.f, 0.f, 0.f, 0.f};
    f32x4 acc[4][4];
    #pragma unroll
    for (int i = 0; i < 4; ++i)
        #pragma unroll
        for (int j = 0; j < 4; ++j)
            acc[i][j] = zero;

    #pragma unroll 1
    for (int kt = 0; kt < 8; ++kt) {
        const int k0 = kt * BK;
        __syncthreads();
        #pragma unroll
        for (int i = 0; i < 4; ++i) {
            int slot = wave * 4 + i;
            int row  = slot * 8 + ar;
            int m    = m0 + row; if (m >= M) m = M - 1;
            __builtin_amdgcn_global_load_lds(
                (const __attribute__((address_space(1))) void*)(xb + (size_t)m * D_FEAT + k0 + ac),
                (__attribute__((address_space(3))) void*)(sA + slot * 512),
                16, 0, 0);
        }
        #pragma unroll
        for (int i = 0; i < 4; ++i) {
            int slot = wave * 4 + i;
            int row  = slot * 8 + ar;
            __builtin_amdgcn_global_load_lds(
                (const __attribute__((address_space(1))) void*)(w1t + (size_t)(n0 + row) * D_FEAT + k0 + ac),
                (__attribute__((address_space(3))) void*)(sB + slot * 512),
                16, 0, 0);
        }
        __syncthreads();
        {
            short8 a[4], b[4];
            #pragma unroll
            for (int mt = 0; mt < 4; ++mt)
                a[mt] = *(const short8*)(sA + (wm + mt * 16 + l15) * 64 + c0);
            #pragma unroll
            for (int nt = 0; nt < 4; ++nt)
                b[nt] = *(const short8*)(sB + (wn + nt * 16 + l15) * 64 + c0);
            #pragma unroll
            for (int mt = 0; mt < 4; ++mt)
                #pragma unroll
                for (int nt = 0; nt < 4; ++nt)
                    acc[mt][nt] = __builtin_amdgcn_mfma_f32_16x16x32_bf16(a[mt], b[nt], acc[mt][nt], 0, 0, 0);
            #pragma unroll
            for (int mt = 0; mt < 4; ++mt)
                a[mt] = *(const short8*)(sA + (wm + mt * 16 + l15) * 64 + c1);
            #pragma unroll
            for (int nt = 0; nt < 4; ++nt)
                b[nt] = *(const short8*)(sB + (wn + nt * 16 + l15) * 64 + c1);
            #pragma unroll
            for (int mt = 0; mt < 4; ++mt)
                #pragma unroll
                for (int nt = 0; nt < 4; ++nt)
                    acc[mt][nt] = __builtin_amdgcn_mfma_f32_16x16x32_bf16(a[mt], b[nt], acc[mt][nt], 0, 0, 0);
        }
    }

    float b1v[4];
    #pragma unroll
    for (int nt = 0; nt < 4; ++nt) {
        int n = n0 + wn + nt * 16 + l15;
        b1v[nt] = (n < D_HID) ? b1[n] : 0.f;
    }
    __syncthreads();
    unsigned short* ep = smem + wave * 4096;   // wave-private [64][64]
    #pragma unroll
    for (int mt = 0; mt < 4; ++mt)
        #pragma unroll
        for (int nt = 0; nt < 4; ++nt)
            #pragma unroll
            for (int r = 0; r < 4; ++r) {
                // C/D layout: row = q*4 + r, col = l15
                float v = acc[mt][nt][r] + b1v[nt];
                ep[(mt * 16 + q * 4 + r) * 64 + nt * 16 + l15] = f2bf(v);
            }
    __syncthreads();
    #pragma unroll
    for (int i = 0; i < 8; ++i) {
        int flat = i * 64 + lane;
        int r  = flat >> 3;
        int c8 = (flat & 7) * 8;
        int m  = m0 + wm + r;
        if (m < M) {
            short8 v = *(const short8*)(ep + r * 64 + c8);
            *(short8*)(UV + (size_t)m * NCOL + n0 + wn + c8) = v;
        }
    }
}

// ---------- kernel 4: per-edge score = relu(U[s]+V[d]) . W2 + b2 ----------
__global__ __launch_bounds__(256) void edge_score_kernel(
    const unsigned short* __restrict__ UV,
    const int* __restrict__ src, const int* __restrict__ dst,
    const float* __restrict__ W2, const float* __restrict__ b2,
    float* __restrict__ out, int E)
{
    const int wave = threadIdx.x >> 6;
    const int lane = threadIdx.x & 63;
    const int e = blockIdx.x * 4 + wave;
    if (e >= E) return;
    const int s = src[e];
    const int d = dst[e];
    const unsigned short* up = UV + (size_t)s * NCOL + lane * 16;
    const unsigned short* vp = UV + (size_t)d * NCOL + D_HID + lane * 16;
    short8 u0 = *(const short8*)up;
    short8 u1 = *(const short8*)(up + 8);
    short8 v0 = *(const short8*)vp;
    short8 v1 = *(const short8*)(vp + 8);
    const float4* wp = (const float4*)(W2 + lane * 16);
    float4 wa = wp[0], wb = wp[1], wc = wp[2], wd = wp[3];
    float w[16] = {wa.x, wa.y, wa.z, wa.w, wb.x, wb.y, wb.z, wb.w,
                   wc.x, wc.y, wc.z, wc.w, wd.x, wd.y, wd.z, wd.w};
    float acc = 0.f;
    #pragma unroll
    for (int k = 0; k < 8; ++k) {
        float h = bf2f((unsigned short)u0[k]) + bf2f((unsigned short)v0[k]);
        acc = fmaf(fmaxf(h, 0.f), w[k], acc);
    }
    #pragma unroll
    for (int k = 0; k < 8; ++k) {
        float h = bf2f((unsigned short)u1[k]) + bf2f((unsigned short)v1[k]);
        acc = fmaf(fmaxf(h, 0.f), w[8 + k], acc);
    }
    #pragma unroll
    for (int off = 1; off < 64; off <<= 1)
        acc += __shfl_xor(acc, off);
    if (lane == 0) out[e] = acc + b2[0];
}

extern "C" void kernel_launch(void* const* d_in, const int* in_sizes, int n_in,
                              void* d_out, int out_size, void* d_ws, size_t ws_size,
                              hipStream_t stream) {
    const float* x   = (const float*)d_in[0];
    const int*   src = (const int*)d_in[1];
    const int*   dst = (const int*)d_in[2];
    const float* W1  = (const float*)d_in[3];
    const float* b1  = (const float*)d_in[4];
    const float* W2  = (const float*)d_in[5];
    const float* b2  = (const float*)d_in[6];
    float* out = (float*)d_out;

    const int M = in_sizes[0] / D_FEAT;   // 50000 nodes
    const int E = in_sizes[1];            // 200000 edges

    // workspace: UV bf16 [M][2048] | xb bf16 [M][512] | w1t bf16 [2048][512]
    char* ws = (char*)d_ws;
    unsigned short* UV  = (unsigned short*)ws;
    unsigned short* xb  = (unsigned short*)(ws + (size_t)M * NCOL * 2);
    unsigned short* w1t = (unsigned short*)(ws + (size_t)M * NCOL * 2 + (size_t)M * D_FEAT * 2);

    const int nx = M * D_FEAT;
    cast_x_kernel<<<(nx / 8 + 255) / 256, 256, 0, stream>>>(x, xb, nx);
    transpose_w1_kernel<<<dim3(32, 16, 2), dim3(32, 8), 0, stream>>>(W1, w1t);
    const int MB = (M + BM - 1) / BM;
    gemm_uv_kernel<<<MB * (NCOL / BN), 256, 0, stream>>>(xb, w1t, b1, UV, M, MB);
    edge_score_kernel<<<(E + 3) / 4, 256, 0, stream>>>(UV, src, dst, W2, b2, out, E);
}

// Round 5
// 378.773 us; speedup vs baseline: 1.3594x; 1.2723x over previous
//
#include <hip/hip_runtime.h>
#include <cstdint>
#include <cstddef>

typedef __attribute__((ext_vector_type(8))) short short8;
typedef __attribute__((ext_vector_type(4))) float f32x4;

#define D_FEAT 512
#define D_HID  1024
#define NCOL   2048   // UV columns = 2*D_HID (U | V)

__device__ __forceinline__ unsigned short f2bf(float f) {
    unsigned u = __builtin_bit_cast(unsigned, f);
    u += 0x7FFFu + ((u >> 16) & 1u);   // round-to-nearest-even
    return (unsigned short)(u >> 16);
}
__device__ __forceinline__ float bf2f(unsigned short h) {
    unsigned u = ((unsigned)h) << 16;
    return __builtin_bit_cast(float, u);
}

// ---------- kernel 1: x fp32 -> bf16 ----------
__global__ __launch_bounds__(256) void cast_x_kernel(const float* __restrict__ x,
                                                     unsigned short* __restrict__ xb,
                                                     int n) {
    int i = (blockIdx.x * 256 + threadIdx.x) * 8;
    if (i >= n) return;
    const float4* xp = (const float4*)(x + i);
    float4 a = xp[0], b = xp[1];
    short8 o;
    o[0] = (short)f2bf(a.x); o[1] = (short)f2bf(a.y);
    o[2] = (short)f2bf(a.z); o[3] = (short)f2bf(a.w);
    o[4] = (short)f2bf(b.x); o[5] = (short)f2bf(b.y);
    o[6] = (short)f2bf(b.z); o[7] = (short)f2bf(b.w);
    *(short8*)(xb + i) = o;
}

// ---------- kernel 2: W1 [1024][1024] fp32 -> w1t bf16 [2048][512] (B^T, U|V stacked) ----------
__global__ __launch_bounds__(256) void transpose_w1_kernel(const float* __restrict__ W1,
                                                           unsigned short* __restrict__ w1t) {
    __shared__ float tile[32][33];
    const int half = blockIdx.z;
    const int kb = blockIdx.y * 32;
    const int nb = blockIdx.x * 32;
    const int tx = threadIdx.x, ty = threadIdx.y;
    #pragma unroll
    for (int i = 0; i < 32; i += 8)
        tile[ty + i][tx] = W1[(size_t)(half * 512 + kb + ty + i) * 1024 + nb + tx];
    __syncthreads();
    #pragma unroll
    for (int i = 0; i < 32; i += 8)
        w1t[(size_t)(half * 1024 + nb + ty + i) * 512 + kb + tx] = f2bf(tile[tx][ty + i]);
}

// ---------- kernel 3: UV = xb @ w1t^T  (M=50000, K=512, N=2048), +b1 on U half, bf16 out ----------
// XOR-swizzled LDS (granule p = cg ^ (row&7)): staging stays wave-uniform+lane*16B
// (global_load_lds constraint) while read-side hits 8 distinct bank clusters (2-way, free).
// 1D grid in supergroups of GM m-blocks x all n-blocks: co-residency window shares one
// A panel (R4 measured: FETCH 409 -> 143 MB).
// launch_bounds min-waves=2: R4 measured that 5 squeezes VGPR to 48, serializing the
// fragment loads (MfmaUtil 29->19) with NO occupancy gain (acc AGPRs bound the budget).
#define BM 128
#define BN 128
#define BK 64
#define GM 32   // m-blocks per supergroup; GM*NB = 512 blocks ~ one residency window

__global__ __launch_bounds__(256, 2) void gemm_uv_kernel(
    const unsigned short* __restrict__ xb,
    const unsigned short* __restrict__ w1t,
    const float* __restrict__ b1,
    unsigned short* __restrict__ UV,
    int M, int MB)   // MB = number of m-blocks
{
    // staging sA+sB = 32 KB; epilogue reuses the same 32 KB (4 waves x [64][64] shorts)
    __shared__ __align__(16) unsigned short smem[16384];
    unsigned short* sA = smem;
    unsigned short* sB = smem + 8192;

    const int NB = NCOL / BN;   // 16
    int bid = blockIdx.x;
    int g    = bid / (GM * NB);
    int rem  = bid - g * (GM * NB);
    int base = g * GM;
    int gm   = MB - base; if (gm > GM) gm = GM;
    int mb   = base + rem % gm;
    int nb   = rem / gm;
    const int m0 = mb * BM;
    const int n0 = nb * BN;

    const int tid  = threadIdx.x;
    const int wave = tid >> 6;
    const int lane = tid & 63;
    const int q    = lane >> 4;
    const int l15  = lane & 15;
    const int wm   = (wave >> 1) * 64;
    const int wn   = (wave & 1) * 64;

    const int ar = lane >> 3;
    const int ac = ((lane & 7) ^ ar) * 8;       // swizzled staging col-group

    const int swz = l15 & 7;
    const int c0 = (q ^ swz) * 8;               // ks = 0
    const int c1 = ((q ^ swz) ^ 4) * 8;         // ks = 32

    f32x4 zero = {0.f, 0.f, 0.f, 0.f};
    f32x4 acc[4][4];
    #pragma unroll
    for (int i = 0; i < 4; ++i)
        #pragma unroll
        for (int j = 0; j < 4; ++j)
            acc[i][j] = zero;

    #pragma unroll 1
    for (int kt = 0; kt < 8; ++kt) {
        const int k0 = kt * BK;
        __syncthreads();
        #pragma unroll
        for (int i = 0; i < 4; ++i) {
            int slot = wave * 4 + i;
            int row  = slot * 8 + ar;
            int m    = m0 + row; if (m >= M) m = M - 1;
            __builtin_amdgcn_global_load_lds(
                (const __attribute__((address_space(1))) void*)(xb + (size_t)m * D_FEAT + k0 + ac),
                (__attribute__((address_space(3))) void*)(sA + slot * 512),
                16, 0, 0);
        }
        #pragma unroll
        for (int i = 0; i < 4; ++i) {
            int slot = wave * 4 + i;
            int row  = slot * 8 + ar;
            __builtin_amdgcn_global_load_lds(
                (const __attribute__((address_space(1))) void*)(w1t + (size_t)(n0 + row) * D_FEAT + k0 + ac),
                (__attribute__((address_space(3))) void*)(sB + slot * 512),
                16, 0, 0);
        }
        __syncthreads();
        {
            short8 a[4], b[4];
            #pragma unroll
            for (int mt = 0; mt < 4; ++mt)
                a[mt] = *(const short8*)(sA + (wm + mt * 16 + l15) * 64 + c0);
            #pragma unroll
            for (int nt = 0; nt < 4; ++nt)
                b[nt] = *(const short8*)(sB + (wn + nt * 16 + l15) * 64 + c0);
            #pragma unroll
            for (int mt = 0; mt < 4; ++mt)
                #pragma unroll
                for (int nt = 0; nt < 4; ++nt)
                    acc[mt][nt] = __builtin_amdgcn_mfma_f32_16x16x32_bf16(a[mt], b[nt], acc[mt][nt], 0, 0, 0);
            #pragma unroll
            for (int mt = 0; mt < 4; ++mt)
                a[mt] = *(const short8*)(sA + (wm + mt * 16 + l15) * 64 + c1);
            #pragma unroll
            for (int nt = 0; nt < 4; ++nt)
                b[nt] = *(const short8*)(sB + (wn + nt * 16 + l15) * 64 + c1);
            #pragma unroll
            for (int mt = 0; mt < 4; ++mt)
                #pragma unroll
                for (int nt = 0; nt < 4; ++nt)
                    acc[mt][nt] = __builtin_amdgcn_mfma_f32_16x16x32_bf16(a[mt], b[nt], acc[mt][nt], 0, 0, 0);
        }
    }

    float b1v[4];
    #pragma unroll
    for (int nt = 0; nt < 4; ++nt) {
        int n = n0 + wn + nt * 16 + l15;
        b1v[nt] = (n < D_HID) ? b1[n] : 0.f;
    }
    __syncthreads();
    unsigned short* ep = smem + wave * 4096;   // wave-private [64][64]
    #pragma unroll
    for (int mt = 0; mt < 4; ++mt)
        #pragma unroll
        for (int nt = 0; nt < 4; ++nt)
            #pragma unroll
            for (int r = 0; r < 4; ++r) {
                // C/D layout: row = q*4 + r, col = l15
                float v = acc[mt][nt][r] + b1v[nt];
                ep[(mt * 16 + q * 4 + r) * 64 + nt * 16 + l15] = f2bf(v);
            }
    __syncthreads();
    #pragma unroll
    for (int i = 0; i < 8; ++i) {
        int flat = i * 64 + lane;
        int r  = flat >> 3;
        int c8 = (flat & 7) * 8;
        int m  = m0 + wm + r;
        if (m < M) {
            short8 v = *(const short8*)(ep + r * 64 + c8);
            *(short8*)(UV + (size_t)m * NCOL + n0 + wn + c8) = v;
        }
    }
}

// ---------- kernel 4: per-edge score = relu(U[s]+V[d]) . W2 + b2 ----------
__global__ __launch_bounds__(256) void edge_score_kernel(
    const unsigned short* __restrict__ UV,
    const int* __restrict__ src, const int* __restrict__ dst,
    const float* __restrict__ W2, const float* __restrict__ b2,
    float* __restrict__ out, int E)
{
    const int wave = threadIdx.x >> 6;
    const int lane = threadIdx.x & 63;
    const int e = blockIdx.x * 4 + wave;
    if (e >= E) return;
    const int s = src[e];
    const int d = dst[e];
    const unsigned short* up = UV + (size_t)s * NCOL + lane * 16;
    const unsigned short* vp = UV + (size_t)d * NCOL + D_HID + lane * 16;
    short8 u0 = *(const short8*)up;
    short8 u1 = *(const short8*)(up + 8);
    short8 v0 = *(const short8*)vp;
    short8 v1 = *(const short8*)(vp + 8);
    const float4* wp = (const float4*)(W2 + lane * 16);
    float4 wa = wp[0], wb = wp[1], wc = wp[2], wd = wp[3];
    float w[16] = {wa.x, wa.y, wa.z, wa.w, wb.x, wb.y, wb.z, wb.w,
                   wc.x, wc.y, wc.z, wc.w, wd.x, wd.y, wd.z, wd.w};
    float acc = 0.f;
    #pragma unroll
    for (int k = 0; k < 8; ++k) {
        float h = bf2f((unsigned short)u0[k]) + bf2f((unsigned short)v0[k]);
        acc = fmaf(fmaxf(h, 0.f), w[k], acc);
    }
    #pragma unroll
    for (int k = 0; k < 8; ++k) {
        float h = bf2f((unsigned short)u1[k]) + bf2f((unsigned short)v1[k]);
        acc = fmaf(fmaxf(h, 0.f), w[8 + k], acc);
    }
    #pragma unroll
    for (int off = 1; off < 64; off <<= 1)
        acc += __shfl_xor(acc, off);
    if (lane == 0) out[e] = acc + b2[0];
}

extern "C" void kernel_launch(void* const* d_in, const int* in_sizes, int n_in,
                              void* d_out, int out_size, void* d_ws, size_t ws_size,
                              hipStream_t stream) {
    const float* x   = (const float*)d_in[0];
    const int*   src = (const int*)d_in[1];
    const int*   dst = (const int*)d_in[2];
    const float* W1  = (const float*)d_in[3];
    const float* b1  = (const float*)d_in[4];
    const float* W2  = (const float*)d_in[5];
    const float* b2  = (const float*)d_in[6];
    float* out = (float*)d_out;

    const int M = in_sizes[0] / D_FEAT;   // 50000 nodes
    const int E = in_sizes[1];            // 200000 edges

    // workspace: UV bf16 [M][2048] | xb bf16 [M][512] | w1t bf16 [2048][512]
    char* ws = (char*)d_ws;
    unsigned short* UV  = (unsigned short*)ws;
    unsigned short* xb  = (unsigned short*)(ws + (size_t)M * NCOL * 2);
    unsigned short* w1t = (unsigned short*)(ws + (size_t)M * NCOL * 2 + (size_t)M * D_FEAT * 2);

    const int nx = M * D_FEAT;
    cast_x_kernel<<<(nx / 8 + 255) / 256, 256, 0, stream>>>(x, xb, nx);
    transpose_w1_kernel<<<dim3(32, 16, 2), dim3(32, 8), 0, stream>>>(W1, w1t);
    const int MB = (M + BM - 1) / BM;
    gemm_uv_kernel<<<MB * (NCOL / BN), 256, 0, stream>>>(xb, w1t, b1, UV, M, MB);
    edge_score_kernel<<<(E + 3) / 4, 256, 0, stream>>>(UV, src, dst, W2, b2, out, E);
}

// Round 6
// 375.180 us; speedup vs baseline: 1.3724x; 1.0096x over previous
//
#include <hip/hip_runtime.h>
#include <cstdint>
#include <cstddef>

typedef __attribute__((ext_vector_type(8))) short short8;
typedef __attribute__((ext_vector_type(4))) float f32x4;

#define D_FEAT 512
#define D_HID  1024
#define NCOL   2048   // UV columns = 2*D_HID (U | V)

__device__ __forceinline__ unsigned short f2bf(float f) {
    unsigned u = __builtin_bit_cast(unsigned, f);
    u += 0x7FFFu + ((u >> 16) & 1u);   // round-to-nearest-even
    return (unsigned short)(u >> 16);
}
__device__ __forceinline__ float bf2f(unsigned short h) {
    unsigned u = ((unsigned)h) << 16;
    return __builtin_bit_cast(float, u);
}

// ---------- kernel 1: x fp32 -> bf16 ----------
__global__ __launch_bounds__(256) void cast_x_kernel(const float* __restrict__ x,
                                                     unsigned short* __restrict__ xb,
                                                     int n) {
    int i = (blockIdx.x * 256 + threadIdx.x) * 8;
    if (i >= n) return;
    const float4* xp = (const float4*)(x + i);
    float4 a = xp[0], b = xp[1];
    short8 o;
    o[0] = (short)f2bf(a.x); o[1] = (short)f2bf(a.y);
    o[2] = (short)f2bf(a.z); o[3] = (short)f2bf(a.w);
    o[4] = (short)f2bf(b.x); o[5] = (short)f2bf(b.y);
    o[6] = (short)f2bf(b.z); o[7] = (short)f2bf(b.w);
    *(short8*)(xb + i) = o;
}

// ---------- kernel 2: W1 [1024][1024] fp32 -> w1t bf16 [2048][512] (B^T, U|V stacked) ----------
__global__ __launch_bounds__(256) void transpose_w1_kernel(const float* __restrict__ W1,
                                                           unsigned short* __restrict__ w1t) {
    __shared__ float tile[32][33];
    const int half = blockIdx.z;
    const int kb = blockIdx.y * 32;
    const int nb = blockIdx.x * 32;
    const int tx = threadIdx.x, ty = threadIdx.y;
    #pragma unroll
    for (int i = 0; i < 32; i += 8)
        tile[ty + i][tx] = W1[(size_t)(half * 512 + kb + ty + i) * 1024 + nb + tx];
    __syncthreads();
    #pragma unroll
    for (int i = 0; i < 32; i += 8)
        w1t[(size_t)(half * 1024 + nb + ty + i) * 512 + kb + tx] = f2bf(tile[tx][ty + i]);
}

// ---------- kernel 3: UV = xb @ w1t^T  (M=50000, K=512, N=2048), +b1 on U half, bf16 out ----------
// XOR-swizzled LDS (granule p = cg ^ (row&7)): staging stays wave-uniform+lane*16B
// (global_load_lds constraint) while read-side hits 8 distinct bank clusters (2-way, free).
// 1D grid in supergroups of GM m-blocks x all n-blocks: co-residency window shares one
// A panel (R4/R5 measured: FETCH 409 -> 85 MB).
// launch_bounds min-waves=2: R4 measured that 5 squeezes VGPR to 48, serializing the
// fragment loads (MfmaUtil 29->19) with NO occupancy gain (acc AGPRs bound the budget).
// R5: 120 us = 874 TF = the m97-structure plateau.
#define BM 128
#define BN 128
#define BK 64
#define GM 32   // m-blocks per supergroup; GM*NB = 512 blocks ~ one residency window

__global__ __launch_bounds__(256, 2) void gemm_uv_kernel(
    const unsigned short* __restrict__ xb,
    const unsigned short* __restrict__ w1t,
    const float* __restrict__ b1,
    unsigned short* __restrict__ UV,
    int M, int MB)   // MB = number of m-blocks
{
    // staging sA+sB = 32 KB; epilogue reuses the same 32 KB (4 waves x [64][64] shorts)
    __shared__ __align__(16) unsigned short smem[16384];
    unsigned short* sA = smem;
    unsigned short* sB = smem + 8192;

    const int NB = NCOL / BN;   // 16
    int bid = blockIdx.x;
    int g    = bid / (GM * NB);
    int rem  = bid - g * (GM * NB);
    int base = g * GM;
    int gm   = MB - base; if (gm > GM) gm = GM;
    int mb   = base + rem % gm;
    int nb   = rem / gm;
    const int m0 = mb * BM;
    const int n0 = nb * BN;

    const int tid  = threadIdx.x;
    const int wave = tid >> 6;
    const int lane = tid & 63;
    const int q    = lane >> 4;
    const int l15  = lane & 15;
    const int wm   = (wave >> 1) * 64;
    const int wn   = (wave & 1) * 64;

    const int ar = lane >> 3;
    const int ac = ((lane & 7) ^ ar) * 8;       // swizzled staging col-group

    const int swz = l15 & 7;
    const int c0 = (q ^ swz) * 8;               // ks = 0
    const int c1 = ((q ^ swz) ^ 4) * 8;         // ks = 32

    f32x4 zero = {0.f, 0.f, 0.f, 0.f};
    f32x4 acc[4][4];
    #pragma unroll
    for (int i = 0; i < 4; ++i)
        #pragma unroll
        for (int j = 0; j < 4; ++j)
            acc[i][j] = zero;

    #pragma unroll 1
    for (int kt = 0; kt < 8; ++kt) {
        const int k0 = kt * BK;
        __syncthreads();
        #pragma unroll
        for (int i = 0; i < 4; ++i) {
            int slot = wave * 4 + i;
            int row  = slot * 8 + ar;
            int m    = m0 + row; if (m >= M) m = M - 1;
            __builtin_amdgcn_global_load_lds(
                (const __attribute__((address_space(1))) void*)(xb + (size_t)m * D_FEAT + k0 + ac),
                (__attribute__((address_space(3))) void*)(sA + slot * 512),
                16, 0, 0);
        }
        #pragma unroll
        for (int i = 0; i < 4; ++i) {
            int slot = wave * 4 + i;
            int row  = slot * 8 + ar;
            __builtin_amdgcn_global_load_lds(
                (const __attribute__((address_space(1))) void*)(w1t + (size_t)(n0 + row) * D_FEAT + k0 + ac),
                (__attribute__((address_space(3))) void*)(sB + slot * 512),
                16, 0, 0);
        }
        __syncthreads();
        {
            short8 a[4], b[4];
            #pragma unroll
            for (int mt = 0; mt < 4; ++mt)
                a[mt] = *(const short8*)(sA + (wm + mt * 16 + l15) * 64 + c0);
            #pragma unroll
            for (int nt = 0; nt < 4; ++nt)
                b[nt] = *(const short8*)(sB + (wn + nt * 16 + l15) * 64 + c0);
            #pragma unroll
            for (int mt = 0; mt < 4; ++mt)
                #pragma unroll
                for (int nt = 0; nt < 4; ++nt)
                    acc[mt][nt] = __builtin_amdgcn_mfma_f32_16x16x32_bf16(a[mt], b[nt], acc[mt][nt], 0, 0, 0);
            #pragma unroll
            for (int mt = 0; mt < 4; ++mt)
                a[mt] = *(const short8*)(sA + (wm + mt * 16 + l15) * 64 + c1);
            #pragma unroll
            for (int nt = 0; nt < 4; ++nt)
                b[nt] = *(const short8*)(sB + (wn + nt * 16 + l15) * 64 + c1);
            #pragma unroll
            for (int mt = 0; mt < 4; ++mt)
                #pragma unroll
                for (int nt = 0; nt < 4; ++nt)
                    acc[mt][nt] = __builtin_amdgcn_mfma_f32_16x16x32_bf16(a[mt], b[nt], acc[mt][nt], 0, 0, 0);
        }
    }

    float b1v[4];
    #pragma unroll
    for (int nt = 0; nt < 4; ++nt) {
        int n = n0 + wn + nt * 16 + l15;
        b1v[nt] = (n < D_HID) ? b1[n] : 0.f;
    }
    __syncthreads();
    unsigned short* ep = smem + wave * 4096;   // wave-private [64][64]
    #pragma unroll
    for (int mt = 0; mt < 4; ++mt)
        #pragma unroll
        for (int nt = 0; nt < 4; ++nt)
            #pragma unroll
            for (int r = 0; r < 4; ++r) {
                // C/D layout: row = q*4 + r, col = l15
                float v = acc[mt][nt][r] + b1v[nt];
                ep[(mt * 16 + q * 4 + r) * 64 + nt * 16 + l15] = f2bf(v);
            }
    __syncthreads();
    #pragma unroll
    for (int i = 0; i < 8; ++i) {
        int flat = i * 64 + lane;
        int r  = flat >> 3;
        int c8 = (flat & 7) * 8;
        int m  = m0 + wm + r;
        if (m < M) {
            short8 v = *(const short8*)(ep + r * 64 + c8);
            *(short8*)(UV + (size_t)m * NCOL + n0 + wn + c8) = v;
        }
    }
}

// ---------- kernel 4: per-edge score = relu(U[s]+V[d]) . W2 + b2 ----------
// 2 edges per wave: 8 row-loads in flight before any vmcnt wait (2x MLP vs 1-edge/wave),
// constant traffic. Butterfly reduce leaves sums on all lanes; lanes 0/1 store.
__global__ __launch_bounds__(256) void edge_score_kernel(
    const unsigned short* __restrict__ UV,
    const int* __restrict__ src, const int* __restrict__ dst,
    const float* __restrict__ W2, const float* __restrict__ b2,
    float* __restrict__ out, int E)
{
    const int wave = threadIdx.x >> 6;
    const int lane = threadIdx.x & 63;
    const int gw = blockIdx.x * 4 + wave;
    const int e0 = gw * 2;
    const int e1 = e0 + 1;
    if (e0 >= E) return;
    const bool has1 = (e1 < E);

    const int s0 = src[e0];
    const int d0 = dst[e0];
    const int s1 = has1 ? src[e1] : s0;
    const int d1 = has1 ? dst[e1] : d0;

    const unsigned short* up0 = UV + (size_t)s0 * NCOL + lane * 16;
    const unsigned short* vp0 = UV + (size_t)d0 * NCOL + D_HID + lane * 16;
    const unsigned short* up1 = UV + (size_t)s1 * NCOL + lane * 16;
    const unsigned short* vp1 = UV + (size_t)d1 * NCOL + D_HID + lane * 16;

    // issue all 8 row loads back-to-back
    short8 a0 = *(const short8*)up0;
    short8 a1 = *(const short8*)(up0 + 8);
    short8 b0 = *(const short8*)vp0;
    short8 b1 = *(const short8*)(vp0 + 8);
    short8 c0 = *(const short8*)up1;
    short8 c1 = *(const short8*)(up1 + 8);
    short8 d0v = *(const short8*)vp1;
    short8 d1v = *(const short8*)(vp1 + 8);

    const float4* wp = (const float4*)(W2 + lane * 16);
    float4 wa = wp[0], wb = wp[1], wc = wp[2], wd = wp[3];
    float w[16] = {wa.x, wa.y, wa.z, wa.w, wb.x, wb.y, wb.z, wb.w,
                   wc.x, wc.y, wc.z, wc.w, wd.x, wd.y, wd.z, wd.w};
    const float bias = b2[0];

    float acc0 = 0.f, acc1 = 0.f;
    #pragma unroll
    for (int k = 0; k < 8; ++k) {
        float h0 = bf2f((unsigned short)a0[k]) + bf2f((unsigned short)b0[k]);
        acc0 = fmaf(fmaxf(h0, 0.f), w[k], acc0);
        float h1 = bf2f((unsigned short)c0[k]) + bf2f((unsigned short)d0v[k]);
        acc1 = fmaf(fmaxf(h1, 0.f), w[k], acc1);
    }
    #pragma unroll
    for (int k = 0; k < 8; ++k) {
        float h0 = bf2f((unsigned short)a1[k]) + bf2f((unsigned short)b1[k]);
        acc0 = fmaf(fmaxf(h0, 0.f), w[8 + k], acc0);
        float h1 = bf2f((unsigned short)c1[k]) + bf2f((unsigned short)d1v[k]);
        acc1 = fmaf(fmaxf(h1, 0.f), w[8 + k], acc1);
    }
    #pragma unroll
    for (int off = 1; off < 64; off <<= 1) {
        acc0 += __shfl_xor(acc0, off);
        acc1 += __shfl_xor(acc1, off);
    }
    if (lane == 0) out[e0] = acc0 + bias;
    if (lane == 1 && has1) out[e1] = acc1 + bias;
}

extern "C" void kernel_launch(void* const* d_in, const int* in_sizes, int n_in,
                              void* d_out, int out_size, void* d_ws, size_t ws_size,
                              hipStream_t stream) {
    const float* x   = (const float*)d_in[0];
    const int*   src = (const int*)d_in[1];
    const int*   dst = (const int*)d_in[2];
    const float* W1  = (const float*)d_in[3];
    const float* b1  = (const float*)d_in[4];
    const float* W2  = (const float*)d_in[5];
    const float* b2  = (const float*)d_in[6];
    float* out = (float*)d_out;

    const int M = in_sizes[0] / D_FEAT;   // 50000 nodes
    const int E = in_sizes[1];            // 200000 edges

    // workspace: UV bf16 [M][2048] | xb bf16 [M][512] | w1t bf16 [2048][512]
    char* ws = (char*)d_ws;
    unsigned short* UV  = (unsigned short*)ws;
    unsigned short* xb  = (unsigned short*)(ws + (size_t)M * NCOL * 2);
    unsigned short* w1t = (unsigned short*)(ws + (size_t)M * NCOL * 2 + (size_t)M * D_FEAT * 2);

    const int nx = M * D_FEAT;
    cast_x_kernel<<<(nx / 8 + 255) / 256, 256, 0, stream>>>(x, xb, nx);
    transpose_w1_kernel<<<dim3(32, 16, 2), dim3(32, 8), 0, stream>>>(W1, w1t);
    const int MB = (M + BM - 1) / BM;
    gemm_uv_kernel<<<MB * (NCOL / BN), 256, 0, stream>>>(xb, w1t, b1, UV, M, MB);
    edge_score_kernel<<<(E + 7) / 8, 256, 0, stream>>>(UV, src, dst, W2, b2, out, E);
}

// Round 7
// 365.295 us; speedup vs baseline: 1.4096x; 1.0271x over previous
//
#include <hip/hip_runtime.h>
#include <cstdint>
#include <cstddef>

typedef __attribute__((ext_vector_type(8))) short short8;
typedef __attribute__((ext_vector_type(4))) float f32x4;

#define D_FEAT 512
#define D_HID  1024
#define NCOL   2048   // hidden cols = 2*D_HID (U | V)
#define NCHUNK 32     // 2048/64 scale chunks per row

__device__ __forceinline__ unsigned short f2bf(float f) {
    unsigned u = __builtin_bit_cast(unsigned, f);
    u += 0x7FFFu + ((u >> 16) & 1u);   // round-to-nearest-even
    return (unsigned short)(u >> 16);
}
__device__ __forceinline__ float i8f(int w, int b) {   // signed byte b of dword -> float
    return (float)((int)(w << (24 - 8 * b)) >> 24);
}

// ---------- kernel 1: x fp32 -> bf16 ----------
__global__ __launch_bounds__(256) void cast_x_kernel(const float* __restrict__ x,
                                                     unsigned short* __restrict__ xb,
                                                     int n) {
    int i = (blockIdx.x * 256 + threadIdx.x) * 8;
    if (i >= n) return;
    const float4* xp = (const float4*)(x + i);
    float4 a = xp[0], b = xp[1];
    short8 o;
    o[0] = (short)f2bf(a.x); o[1] = (short)f2bf(a.y);
    o[2] = (short)f2bf(a.z); o[3] = (short)f2bf(a.w);
    o[4] = (short)f2bf(b.x); o[5] = (short)f2bf(b.y);
    o[6] = (short)f2bf(b.z); o[7] = (short)f2bf(b.w);
    *(short8*)(xb + i) = o;
}

// ---------- kernel 2: W1 [1024][1024] fp32 -> w1t bf16 [2048][512] (B^T, U|V stacked) ----------
__global__ __launch_bounds__(256) void transpose_w1_kernel(const float* __restrict__ W1,
                                                           unsigned short* __restrict__ w1t) {
    __shared__ float tile[32][33];
    const int half = blockIdx.z;
    const int kb = blockIdx.y * 32;
    const int nb = blockIdx.x * 32;
    const int tx = threadIdx.x, ty = threadIdx.y;
    #pragma unroll
    for (int i = 0; i < 32; i += 8)
        tile[ty + i][tx] = W1[(size_t)(half * 512 + kb + ty + i) * 1024 + nb + tx];
    __syncthreads();
    #pragma unroll
    for (int i = 0; i < 32; i += 8)
        w1t[(size_t)(half * 1024 + nb + ty + i) * 512 + kb + tx] = f2bf(tile[tx][ty + i]);
}

// ---------- kernel 3: qUV = quant_i8(xb @ w1t^T + b1)  with per-(row,64col) scales ----------
// K-loop identical to R5/R6 (874 TF plateau): XOR-swizzled LDS + supergroup grid.
// Epilogue: +b1, per-(row, 64-col wave tile) absmax via 4 in-lane maxes + 4 shfl_xor,
// int8 quantize, LDS repack, 16B stores. Edge traffic halves (R6: edge at ~3.7 TB/s
// path floor; bytes are the only lever left — order costs more than it buys, R3).
#define BM 128
#define BN 128
#define BK 64
#define GM 32   // m-blocks per supergroup; GM*NB = 512 blocks ~ one residency window

__global__ __launch_bounds__(256, 2) void gemm_uv_kernel(
    const unsigned short* __restrict__ xb,
    const unsigned short* __restrict__ w1t,
    const float* __restrict__ b1,
    signed char* __restrict__ qUV,        // [M][2048] int8
    float* __restrict__ scales,           // [M][32] fp32
    int M, int MB)
{
    __shared__ __align__(16) unsigned short smem[16384];   // 32 KB
    unsigned short* sA = smem;
    unsigned short* sB = smem + 8192;

    const int NB = NCOL / BN;   // 16
    int bid = blockIdx.x;
    int g    = bid / (GM * NB);
    int rem  = bid - g * (GM * NB);
    int base = g * GM;
    int gm   = MB - base; if (gm > GM) gm = GM;
    int mb   = base + rem % gm;
    int nb   = rem / gm;
    const int m0 = mb * BM;
    const int n0 = nb * BN;

    const int tid  = threadIdx.x;
    const int wave = tid >> 6;
    const int lane = tid & 63;
    const int q    = lane >> 4;
    const int l15  = lane & 15;
    const int wm   = (wave >> 1) * 64;
    const int wn   = (wave & 1) * 64;

    const int ar = lane >> 3;
    const int ac = ((lane & 7) ^ ar) * 8;       // swizzled staging col-group

    const int swz = l15 & 7;
    const int c0 = (q ^ swz) * 8;               // ks = 0
    const int c1 = ((q ^ swz) ^ 4) * 8;         // ks = 32

    f32x4 zero = {0.f, 0.f, 0.f, 0.f};
    f32x4 acc[4][4];
    #pragma unroll
    for (int i = 0; i < 4; ++i)
        #pragma unroll
        for (int j = 0; j < 4; ++j)
            acc[i][j] = zero;

    #pragma unroll 1
    for (int kt = 0; kt < 8; ++kt) {
        const int k0 = kt * BK;
        __syncthreads();
        #pragma unroll
        for (int i = 0; i < 4; ++i) {
            int slot = wave * 4 + i;
            int row  = slot * 8 + ar;
            int m    = m0 + row; if (m >= M) m = M - 1;
            __builtin_amdgcn_global_load_lds(
                (const __attribute__((address_space(1))) void*)(xb + (size_t)m * D_FEAT + k0 + ac),
                (__attribute__((address_space(3))) void*)(sA + slot * 512),
                16, 0, 0);
        }
        #pragma unroll
        for (int i = 0; i < 4; ++i) {
            int slot = wave * 4 + i;
            int row  = slot * 8 + ar;
            __builtin_amdgcn_global_load_lds(
                (const __attribute__((address_space(1))) void*)(w1t + (size_t)(n0 + row) * D_FEAT + k0 + ac),
                (__attribute__((address_space(3))) void*)(sB + slot * 512),
                16, 0, 0);
        }
        __syncthreads();
        {
            short8 a[4], b[4];
            #pragma unroll
            for (int mt = 0; mt < 4; ++mt)
                a[mt] = *(const short8*)(sA + (wm + mt * 16 + l15) * 64 + c0);
            #pragma unroll
            for (int nt = 0; nt < 4; ++nt)
                b[nt] = *(const short8*)(sB + (wn + nt * 16 + l15) * 64 + c0);
            #pragma unroll
            for (int mt = 0; mt < 4; ++mt)
                #pragma unroll
                for (int nt = 0; nt < 4; ++nt)
                    acc[mt][nt] = __builtin_amdgcn_mfma_f32_16x16x32_bf16(a[mt], b[nt], acc[mt][nt], 0, 0, 0);
            #pragma unroll
            for (int mt = 0; mt < 4; ++mt)
                a[mt] = *(const short8*)(sA + (wm + mt * 16 + l15) * 64 + c1);
            #pragma unroll
            for (int nt = 0; nt < 4; ++nt)
                b[nt] = *(const short8*)(sB + (wn + nt * 16 + l15) * 64 + c1);
            #pragma unroll
            for (int mt = 0; mt < 4; ++mt)
                #pragma unroll
                for (int nt = 0; nt < 4; ++nt)
                    acc[mt][nt] = __builtin_amdgcn_mfma_f32_16x16x32_bf16(a[mt], b[nt], acc[mt][nt], 0, 0, 0);
        }
    }

    // ---- epilogue: bias, per-row-chunk absmax, int8 quantize ----
    float b1v[4];
    #pragma unroll
    for (int nt = 0; nt < 4; ++nt) {
        int n = n0 + wn + nt * 16 + l15;
        b1v[nt] = (n < D_HID) ? b1[n] : 0.f;
    }
    #pragma unroll
    for (int mt = 0; mt < 4; ++mt)
        #pragma unroll
        for (int nt = 0; nt < 4; ++nt)
            #pragma unroll
            for (int r = 0; r < 4; ++r)
                acc[mt][nt][r] += b1v[nt];

    // row absmax over this wave's 64 cols: in-lane over nt, then shfl over l15 (q preserved)
    float sc[4][4], inv[4][4];   // [mt][r]
    #pragma unroll
    for (int mt = 0; mt < 4; ++mt)
        #pragma unroll
        for (int r = 0; r < 4; ++r) {
            float m_ = fmaxf(fmaxf(fabsf(acc[mt][0][r]), fabsf(acc[mt][1][r])),
                             fmaxf(fabsf(acc[mt][2][r]), fabsf(acc[mt][3][r])));
            #pragma unroll
            for (int off = 1; off < 16; off <<= 1)
                m_ = fmaxf(m_, __shfl_xor(m_, off));
            sc[mt][r]  = m_ * (1.0f / 127.0f);
            inv[mt][r] = (m_ > 0.f) ? (127.0f / m_) : 0.f;
        }

    __syncthreads();   // all waves done reading sA/sB
    char* ep8 = (char*)smem + wave * 4096;   // wave-private [64][64] int8
    #pragma unroll
    for (int mt = 0; mt < 4; ++mt)
        #pragma unroll
        for (int nt = 0; nt < 4; ++nt)
            #pragma unroll
            for (int r = 0; r < 4; ++r) {
                float qv = rintf(acc[mt][nt][r] * inv[mt][r]);
                qv = fminf(fmaxf(qv, -127.f), 127.f);
                ep8[(mt * 16 + q * 4 + r) * 64 + nt * 16 + l15] = (signed char)(int)qv;
            }
    // scale store: lanes with l15==0 hold the max for rows q*4+r
    const int chunk = (n0 + wn) >> 6;
    if (l15 == 0) {
        #pragma unroll
        for (int mt = 0; mt < 4; ++mt)
            #pragma unroll
            for (int r = 0; r < 4; ++r) {
                int m = m0 + wm + mt * 16 + q * 4 + r;
                if (m < M) scales[(size_t)m * NCHUNK + chunk] = sc[mt][r];
            }
    }
    // same-wave LDS write->read: no barrier needed (wave-private region)
    #pragma unroll
    for (int i = 0; i < 4; ++i) {
        int flat = i * 64 + lane;          // 0..255
        int r   = flat >> 2;               // row 0..63
        int c16 = (flat & 3) * 16;
        int m   = m0 + wm + r;
        if (m < M) {
            int4 v = *(const int4*)(ep8 + r * 64 + c16);
            *(int4*)(qUV + (size_t)m * NCOL + n0 + wn + c16) = v;
        }
    }
}

// ---------- kernel 4: per-edge score = relu(sU*qU[s] + sV*qV[d]) . W2 + b2 ----------
// int8 rows: 1 KB U + 1 KB V per edge (half of bf16). 2 edges/wave.
__global__ __launch_bounds__(256) void edge_score_kernel(
    const signed char* __restrict__ qUV,
    const float* __restrict__ scales,
    const int* __restrict__ src, const int* __restrict__ dst,
    const float* __restrict__ W2, const float* __restrict__ b2,
    float* __restrict__ out, int E)
{
    const int wave = threadIdx.x >> 6;
    const int lane = threadIdx.x & 63;
    const int gw = blockIdx.x * 4 + wave;
    const int e0 = gw * 2;
    const int e1 = e0 + 1;
    if (e0 >= E) return;
    const bool has1 = (e1 < E);

    const int s0 = src[e0];
    const int d0 = dst[e0];
    const int s1 = has1 ? src[e1] : s0;
    const int d1 = has1 ? dst[e1] : d0;

    // lane l covers cols l*16..l*16+15 (U) and 1024+l*16.. (V); chunk = l>>2
    int4 qu0 = *(const int4*)(qUV + (size_t)s0 * NCOL + lane * 16);
    int4 qv0 = *(const int4*)(qUV + (size_t)d0 * NCOL + D_HID + lane * 16);
    int4 qu1 = *(const int4*)(qUV + (size_t)s1 * NCOL + lane * 16);
    int4 qv1 = *(const int4*)(qUV + (size_t)d1 * NCOL + D_HID + lane * 16);
    const int ch = lane >> 2;
    float su0 = scales[(size_t)s0 * NCHUNK + ch];
    float sv0 = scales[(size_t)d0 * NCHUNK + 16 + ch];
    float su1 = scales[(size_t)s1 * NCHUNK + ch];
    float sv1 = scales[(size_t)d1 * NCHUNK + 16 + ch];

    const float4* wp = (const float4*)(W2 + lane * 16);
    float4 wa = wp[0], wb = wp[1], wc = wp[2], wd = wp[3];
    float w[16] = {wa.x, wa.y, wa.z, wa.w, wb.x, wb.y, wb.z, wb.w,
                   wc.x, wc.y, wc.z, wc.w, wd.x, wd.y, wd.z, wd.w};
    const float bias = b2[0];

    const int* u0w = (const int*)&qu0; const int* v0w = (const int*)&qv0;
    const int* u1w = (const int*)&qu1; const int* v1w = (const int*)&qv1;

    float acc0 = 0.f, acc1 = 0.f;
    #pragma unroll
    for (int dw = 0; dw < 4; ++dw) {
        #pragma unroll
        for (int b = 0; b < 4; ++b) {
            int k = dw * 4 + b;
            float h0 = fmaf(i8f(u0w[dw], b), su0, i8f(v0w[dw], b) * sv0);
            acc0 = fmaf(fmaxf(h0, 0.f), w[k], acc0);
            float h1 = fmaf(i8f(u1w[dw], b), su1, i8f(v1w[dw], b) * sv1);
            acc1 = fmaf(fmaxf(h1, 0.f), w[k], acc1);
        }
    }
    #pragma unroll
    for (int off = 1; off < 64; off <<= 1) {
        acc0 += __shfl_xor(acc0, off);
        acc1 += __shfl_xor(acc1, off);
    }
    if (lane == 0) out[e0] = acc0 + bias;
    if (lane == 1 && has1) out[e1] = acc1 + bias;
}

extern "C" void kernel_launch(void* const* d_in, const int* in_sizes, int n_in,
                              void* d_out, int out_size, void* d_ws, size_t ws_size,
                              hipStream_t stream) {
    const float* x   = (const float*)d_in[0];
    const int*   src = (const int*)d_in[1];
    const int*   dst = (const int*)d_in[2];
    const float* W1  = (const float*)d_in[3];
    const float* b1  = (const float*)d_in[4];
    const float* W2  = (const float*)d_in[5];
    const float* b2  = (const float*)d_in[6];
    float* out = (float*)d_out;

    const int M = in_sizes[0] / D_FEAT;   // 50000 nodes
    const int E = in_sizes[1];            // 200000 edges

    // workspace: qUV i8 [M][2048] | scales f32 [M][32] | xb bf16 [M][512] | w1t bf16 [2048][512]
    char* ws = (char*)d_ws;
    signed char*   qUV    = (signed char*)ws;
    float*         scales = (float*)(ws + (size_t)M * NCOL);
    unsigned short* xb    = (unsigned short*)(ws + (size_t)M * NCOL + (size_t)M * NCHUNK * 4);
    unsigned short* w1t   = (unsigned short*)(ws + (size_t)M * NCOL + (size_t)M * NCHUNK * 4
                                                 + (size_t)M * D_FEAT * 2);

    const int nx = M * D_FEAT;
    cast_x_kernel<<<(nx / 8 + 255) / 256, 256, 0, stream>>>(x, xb, nx);
    transpose_w1_kernel<<<dim3(32, 16, 2), dim3(32, 8), 0, stream>>>(W1, w1t);
    const int MB = (M + BM - 1) / BM;
    gemm_uv_kernel<<<MB * (NCOL / BN), 256, 0, stream>>>(xb, w1t, b1, qUV, scales, M, MB);
    edge_score_kernel<<<(E + 7) / 8, 256, 0, stream>>>(qUV, scales, src, dst, W2, b2, out, E);
}

// Round 8
// 363.830 us; speedup vs baseline: 1.4152x; 1.0040x over previous
//
#include <hip/hip_runtime.h>
#include <cstdint>
#include <cstddef>

typedef __attribute__((ext_vector_type(8))) short short8;
typedef __attribute__((ext_vector_type(4))) float f32x4;

#define D_FEAT 512
#define D_HID  1024
#define NCOL   2048   // hidden cols = 2*D_HID (U | V)
#define NCHUNK 32     // 2048/64 scale chunks per row

__device__ __forceinline__ unsigned short f2bf(float f) {
    unsigned u = __builtin_bit_cast(unsigned, f);
    u += 0x7FFFu + ((u >> 16) & 1u);   // round-to-nearest-even
    return (unsigned short)(u >> 16);
}

// ---------- kernel 1: x fp32 -> bf16 ----------
__global__ __launch_bounds__(256) void cast_x_kernel(const float* __restrict__ x,
                                                     unsigned short* __restrict__ xb,
                                                     int n) {
    int i = (blockIdx.x * 256 + threadIdx.x) * 8;
    if (i >= n) return;
    const float4* xp = (const float4*)(x + i);
    float4 a = xp[0], b = xp[1];
    short8 o;
    o[0] = (short)f2bf(a.x); o[1] = (short)f2bf(a.y);
    o[2] = (short)f2bf(a.z); o[3] = (short)f2bf(a.w);
    o[4] = (short)f2bf(b.x); o[5] = (short)f2bf(b.y);
    o[6] = (short)f2bf(b.z); o[7] = (short)f2bf(b.w);
    *(short8*)(xb + i) = o;
}

// ---------- kernel 2: W1 [1024][1024] fp32 -> w1t bf16 [2048][512] (B^T, U|V stacked) ----------
__global__ __launch_bounds__(256) void transpose_w1_kernel(const float* __restrict__ W1,
                                                           unsigned short* __restrict__ w1t) {
    __shared__ float tile[32][33];
    const int half = blockIdx.z;
    const int kb = blockIdx.y * 32;
    const int nb = blockIdx.x * 32;
    const int tx = threadIdx.x, ty = threadIdx.y;
    #pragma unroll
    for (int i = 0; i < 32; i += 8)
        tile[ty + i][tx] = W1[(size_t)(half * 512 + kb + ty + i) * 1024 + nb + tx];
    __syncthreads();
    #pragma unroll
    for (int i = 0; i < 32; i += 8)
        w1t[(size_t)(half * 1024 + nb + ty + i) * 512 + kb + tx] = f2bf(tile[tx][ty + i]);
}

// ---------- kernel 3: qUV = quant_u8(xb @ w1t^T + b1)  with per-(row,64col) scales ----------
// K-loop: R5's 874-TF plateau structure (XOR-swizzled LDS + supergroup grid).
// Epilogue (R7 lesson: rint/clamp/cvt cost +28us VALU): magic-number quantize —
// inv=127/max guarantees |t*inv|<=127, so fmaf(t, inv, 12583040.0f) leaves
// rint(t*inv)+128 in the low byte (biased uint8); ds_write_b8 takes low byte. 1 fmaf/elem.
#define BM 128
#define BN 128
#define BK 64
#define GM 32   // m-blocks per supergroup; GM*NB = 512 blocks ~ one residency window

__global__ __launch_bounds__(256, 2) void gemm_uv_kernel(
    const unsigned short* __restrict__ xb,
    const unsigned short* __restrict__ w1t,
    const float* __restrict__ b1,
    unsigned char* __restrict__ qUV,      // [M][2048] uint8 (biased +128)
    float* __restrict__ scales,           // [M][32] fp32
    int M, int MB)
{
    __shared__ __align__(16) unsigned short smem[16384];   // 32 KB
    unsigned short* sA = smem;
    unsigned short* sB = smem + 8192;

    const int NB = NCOL / BN;   // 16
    int bid = blockIdx.x;
    int g    = bid / (GM * NB);
    int rem  = bid - g * (GM * NB);
    int base = g * GM;
    int gm   = MB - base; if (gm > GM) gm = GM;
    int mb   = base + rem % gm;
    int nb   = rem / gm;
    const int m0 = mb * BM;
    const int n0 = nb * BN;

    const int tid  = threadIdx.x;
    const int wave = tid >> 6;
    const int lane = tid & 63;
    const int q    = lane >> 4;
    const int l15  = lane & 15;
    const int wm   = (wave >> 1) * 64;
    const int wn   = (wave & 1) * 64;

    const int ar = lane >> 3;
    const int ac = ((lane & 7) ^ ar) * 8;       // swizzled staging col-group

    const int swz = l15 & 7;
    const int c0 = (q ^ swz) * 8;               // ks = 0
    const int c1 = ((q ^ swz) ^ 4) * 8;         // ks = 32

    f32x4 zero = {0.f, 0.f, 0.f, 0.f};
    f32x4 acc[4][4];
    #pragma unroll
    for (int i = 0; i < 4; ++i)
        #pragma unroll
        for (int j = 0; j < 4; ++j)
            acc[i][j] = zero;

    #pragma unroll 1
    for (int kt = 0; kt < 8; ++kt) {
        const int k0 = kt * BK;
        __syncthreads();
        #pragma unroll
        for (int i = 0; i < 4; ++i) {
            int slot = wave * 4 + i;
            int row  = slot * 8 + ar;
            int m    = m0 + row; if (m >= M) m = M - 1;
            __builtin_amdgcn_global_load_lds(
                (const __attribute__((address_space(1))) void*)(xb + (size_t)m * D_FEAT + k0 + ac),
                (__attribute__((address_space(3))) void*)(sA + slot * 512),
                16, 0, 0);
        }
        #pragma unroll
        for (int i = 0; i < 4; ++i) {
            int slot = wave * 4 + i;
            int row  = slot * 8 + ar;
            __builtin_amdgcn_global_load_lds(
                (const __attribute__((address_space(1))) void*)(w1t + (size_t)(n0 + row) * D_FEAT + k0 + ac),
                (__attribute__((address_space(3))) void*)(sB + slot * 512),
                16, 0, 0);
        }
        __syncthreads();
        {
            short8 a[4], b[4];
            #pragma unroll
            for (int mt = 0; mt < 4; ++mt)
                a[mt] = *(const short8*)(sA + (wm + mt * 16 + l15) * 64 + c0);
            #pragma unroll
            for (int nt = 0; nt < 4; ++nt)
                b[nt] = *(const short8*)(sB + (wn + nt * 16 + l15) * 64 + c0);
            #pragma unroll
            for (int mt = 0; mt < 4; ++mt)
                #pragma unroll
                for (int nt = 0; nt < 4; ++nt)
                    acc[mt][nt] = __builtin_amdgcn_mfma_f32_16x16x32_bf16(a[mt], b[nt], acc[mt][nt], 0, 0, 0);
            #pragma unroll
            for (int mt = 0; mt < 4; ++mt)
                a[mt] = *(const short8*)(sA + (wm + mt * 16 + l15) * 64 + c1);
            #pragma unroll
            for (int nt = 0; nt < 4; ++nt)
                b[nt] = *(const short8*)(sB + (wn + nt * 16 + l15) * 64 + c1);
            #pragma unroll
            for (int mt = 0; mt < 4; ++mt)
                #pragma unroll
                for (int nt = 0; nt < 4; ++nt)
                    acc[mt][nt] = __builtin_amdgcn_mfma_f32_16x16x32_bf16(a[mt], b[nt], acc[mt][nt], 0, 0, 0);
        }
    }

    // ---- epilogue: bias, per-(row,64col) absmax, magic-fmaf uint8 quantize ----
    float b1v[4];
    #pragma unroll
    for (int nt = 0; nt < 4; ++nt) {
        int n = n0 + wn + nt * 16 + l15;
        b1v[nt] = (n < D_HID) ? b1[n] : 0.f;
    }
    #pragma unroll
    for (int mt = 0; mt < 4; ++mt)
        #pragma unroll
        for (int nt = 0; nt < 4; ++nt)
            #pragma unroll
            for (int r = 0; r < 4; ++r)
                acc[mt][nt][r] += b1v[nt];

    float sc[4][4], inv[4][4];   // [mt][r]
    #pragma unroll
    for (int mt = 0; mt < 4; ++mt)
        #pragma unroll
        for (int r = 0; r < 4; ++r) {
            float m_ = fmaxf(fmaxf(fabsf(acc[mt][0][r]), fabsf(acc[mt][1][r])),
                             fmaxf(fabsf(acc[mt][2][r]), fabsf(acc[mt][3][r])));
            #pragma unroll
            for (int off = 1; off < 16; off <<= 1)
                m_ = fmaxf(m_, __shfl_xor(m_, off));
            sc[mt][r]  = m_ * (1.0f / 127.0f);
            inv[mt][r] = (m_ > 0.f) ? (127.0f / m_) : 0.f;
        }

    __syncthreads();   // all waves done reading sA/sB
    unsigned char* ep8 = (unsigned char*)smem + wave * 4096;   // wave-private [64][64] u8
    const float MAGIC = 12583040.0f;   // 1.5*2^23 + 128: low byte = rint(x)+128
    #pragma unroll
    for (int mt = 0; mt < 4; ++mt)
        #pragma unroll
        for (int nt = 0; nt < 4; ++nt)
            #pragma unroll
            for (int r = 0; r < 4; ++r) {
                float f = fmaf(acc[mt][nt][r], inv[mt][r], MAGIC);
                ep8[(mt * 16 + q * 4 + r) * 64 + nt * 16 + l15] =
                    (unsigned char)__builtin_bit_cast(unsigned, f);
            }
    const int chunk = (n0 + wn) >> 6;
    if (l15 == 0) {
        #pragma unroll
        for (int mt = 0; mt < 4; ++mt)
            #pragma unroll
            for (int r = 0; r < 4; ++r) {
                int m = m0 + wm + mt * 16 + q * 4 + r;
                if (m < M) scales[(size_t)m * NCHUNK + chunk] = sc[mt][r];
            }
    }
    // same-wave LDS write->read: wave-private region, no barrier needed
    #pragma unroll
    for (int i = 0; i < 4; ++i) {
        int flat = i * 64 + lane;          // 0..255
        int r   = flat >> 2;               // row 0..63
        int c16 = (flat & 3) * 16;
        int m   = m0 + wm + r;
        if (m < M) {
            int4 v = *(const int4*)(ep8 + r * 64 + c16);
            *(int4*)(qUV + (size_t)m * NCOL + n0 + wn + c16) = v;
        }
    }
}

// ---------- kernel 4: per-edge score = relu(sU*(qU-128) + sV*(qV-128)) . W2 + b2 ----------
__global__ __launch_bounds__(256) void edge_score_kernel(
    const unsigned char* __restrict__ qUV,
    const float* __restrict__ scales,
    const int* __restrict__ src, const int* __restrict__ dst,
    const float* __restrict__ W2, const float* __restrict__ b2,
    float* __restrict__ out, int E)
{
    const int wave = threadIdx.x >> 6;
    const int lane = threadIdx.x & 63;
    const int gw = blockIdx.x * 4 + wave;
    const int e0 = gw * 2;
    const int e1 = e0 + 1;
    if (e0 >= E) return;
    const bool has1 = (e1 < E);

    const int s0 = src[e0];
    const int d0 = dst[e0];
    const int s1 = has1 ? src[e1] : s0;
    const int d1 = has1 ? dst[e1] : d0;

    uint4 qu0 = *(const uint4*)(qUV + (size_t)s0 * NCOL + lane * 16);
    uint4 qv0 = *(const uint4*)(qUV + (size_t)d0 * NCOL + D_HID + lane * 16);
    uint4 qu1 = *(const uint4*)(qUV + (size_t)s1 * NCOL + lane * 16);
    uint4 qv1 = *(const uint4*)(qUV + (size_t)d1 * NCOL + D_HID + lane * 16);
    const int ch = lane >> 2;
    float su0 = scales[(size_t)s0 * NCHUNK + ch];
    float sv0 = scales[(size_t)d0 * NCHUNK + 16 + ch];
    float su1 = scales[(size_t)s1 * NCHUNK + ch];
    float sv1 = scales[(size_t)d1 * NCHUNK + 16 + ch];
    // h = su*(ub-128) + sv*(vb-128) = fmaf(ub,su, fmaf(vb,sv, cc)), cc = -128*(su+sv)
    float cc0 = -128.0f * (su0 + sv0);
    float cc1 = -128.0f * (su1 + sv1);

    const float4* wp = (const float4*)(W2 + lane * 16);
    float4 wa = wp[0], wb = wp[1], wc = wp[2], wd = wp[3];
    float w[16] = {wa.x, wa.y, wa.z, wa.w, wb.x, wb.y, wb.z, wb.w,
                   wc.x, wc.y, wc.z, wc.w, wd.x, wd.y, wd.z, wd.w};
    const float bias = b2[0];

    const unsigned* u0w = (const unsigned*)&qu0; const unsigned* v0w = (const unsigned*)&qv0;
    const unsigned* u1w = (const unsigned*)&qu1; const unsigned* v1w = (const unsigned*)&qv1;

    float acc0 = 0.f, acc1 = 0.f;
    #pragma unroll
    for (int dw = 0; dw < 4; ++dw) {
        #pragma unroll
        for (int b = 0; b < 4; ++b) {
            int k = dw * 4 + b;
            // (float)((w>>8b)&0xFF) -> v_cvt_f32_ubyte[b]
            float ub0 = (float)((u0w[dw] >> (8 * b)) & 0xFFu);
            float vb0 = (float)((v0w[dw] >> (8 * b)) & 0xFFu);
            float h0 = fmaf(ub0, su0, fmaf(vb0, sv0, cc0));
            acc0 = fmaf(fmaxf(h0, 0.f), w[k], acc0);
            float ub1 = (float)((u1w[dw] >> (8 * b)) & 0xFFu);
            float vb1 = (float)((v1w[dw] >> (8 * b)) & 0xFFu);
            float h1 = fmaf(ub1, su1, fmaf(vb1, sv1, cc1));
            acc1 = fmaf(fmaxf(h1, 0.f), w[k], acc1);
        }
    }
    #pragma unroll
    for (int off = 1; off < 64; off <<= 1) {
        acc0 += __shfl_xor(acc0, off);
        acc1 += __shfl_xor(acc1, off);
    }
    if (lane == 0) out[e0] = acc0 + bias;
    if (lane == 1 && has1) out[e1] = acc1 + bias;
}

extern "C" void kernel_launch(void* const* d_in, const int* in_sizes, int n_in,
                              void* d_out, int out_size, void* d_ws, size_t ws_size,
                              hipStream_t stream) {
    const float* x   = (const float*)d_in[0];
    const int*   src = (const int*)d_in[1];
    const int*   dst = (const int*)d_in[2];
    const float* W1  = (const float*)d_in[3];
    const float* b1  = (const float*)d_in[4];
    const float* W2  = (const float*)d_in[5];
    const float* b2  = (const float*)d_in[6];
    float* out = (float*)d_out;

    const int M = in_sizes[0] / D_FEAT;   // 50000 nodes
    const int E = in_sizes[1];            // 200000 edges

    // workspace: qUV u8 [M][2048] | scales f32 [M][32] | xb bf16 [M][512] | w1t bf16 [2048][512]
    char* ws = (char*)d_ws;
    unsigned char*  qUV    = (unsigned char*)ws;
    float*          scales = (float*)(ws + (size_t)M * NCOL);
    unsigned short* xb     = (unsigned short*)(ws + (size_t)M * NCOL + (size_t)M * NCHUNK * 4);
    unsigned short* w1t    = (unsigned short*)(ws + (size_t)M * NCOL + (size_t)M * NCHUNK * 4
                                                  + (size_t)M * D_FEAT * 2);

    const int nx = M * D_FEAT;
    cast_x_kernel<<<(nx / 8 + 255) / 256, 256, 0, stream>>>(x, xb, nx);
    transpose_w1_kernel<<<dim3(32, 16, 2), dim3(32, 8), 0, stream>>>(W1, w1t);
    const int MB = (M + BM - 1) / BM;
    gemm_uv_kernel<<<MB * (NCOL / BN), 256, 0, stream>>>(xb, w1t, b1, qUV, scales, M, MB);
    edge_score_kernel<<<(E + 7) / 8, 256, 0, stream>>>(qUV, scales, src, dst, W2, b2, out, E);
}

// Round 9
// 346.300 us; speedup vs baseline: 1.4869x; 1.0506x over previous
//
#include <hip/hip_runtime.h>
#include <cstdint>
#include <cstddef>

typedef __attribute__((ext_vector_type(8))) short short8;
typedef __attribute__((ext_vector_type(4))) float f32x4;

#define D_FEAT 512
#define D_HID  1024
#define NCOL   2048   // hidden cols = 2*D_HID (U | V)
#define NCHUNK 32     // 2048/64 scale chunks per row

__device__ __forceinline__ unsigned short f2bf(float f) {
    unsigned u = __builtin_bit_cast(unsigned, f);
    u += 0x7FFFu + ((u >> 16) & 1u);   // round-to-nearest-even
    return (unsigned short)(u >> 16);
}

// ---------- kernel 1: x fp32 -> bf16 ----------
__global__ __launch_bounds__(256) void cast_x_kernel(const float* __restrict__ x,
                                                     unsigned short* __restrict__ xb,
                                                     int n) {
    int i = (blockIdx.x * 256 + threadIdx.x) * 8;
    if (i >= n) return;
    const float4* xp = (const float4*)(x + i);
    float4 a = xp[0], b = xp[1];
    short8 o;
    o[0] = (short)f2bf(a.x); o[1] = (short)f2bf(a.y);
    o[2] = (short)f2bf(a.z); o[3] = (short)f2bf(a.w);
    o[4] = (short)f2bf(b.x); o[5] = (short)f2bf(b.y);
    o[6] = (short)f2bf(b.z); o[7] = (short)f2bf(b.w);
    *(short8*)(xb + i) = o;
}

// ---------- kernel 2: W1 [1024][1024] fp32 -> w1t bf16 [2048][512] (B^T, U|V stacked) ----------
__global__ __launch_bounds__(256) void transpose_w1_kernel(const float* __restrict__ W1,
                                                           unsigned short* __restrict__ w1t) {
    __shared__ float tile[32][33];
    const int half = blockIdx.z;
    const int kb = blockIdx.y * 32;
    const int nb = blockIdx.x * 32;
    const int tx = threadIdx.x, ty = threadIdx.y;
    #pragma unroll
    for (int i = 0; i < 32; i += 8)
        tile[ty + i][tx] = W1[(size_t)(half * 512 + kb + ty + i) * 1024 + nb + tx];
    __syncthreads();
    #pragma unroll
    for (int i = 0; i < 32; i += 8)
        w1t[(size_t)(half * 1024 + nb + ty + i) * 512 + kb + tx] = f2bf(tile[tx][ty + i]);
}

// ---------- kernel 3: qUV = quant_u8(xb @ w1t^T + b1)  with per-(16row,64col) scales ----------
// K-loop: R5's 874-TF plateau structure (XOR-swizzled LDS + supergroup grid).
// Epilogue (R8 lesson — VALU model closes: absmax tree + fp division were the cost):
//   acc seeded with b1 (free bias), per-mt 16-row-group absmax via in-lane max +
//   6-step full-wave butterfly (4 chains not 16), v_rcp for 127/max, magic-fmaf
//   uint8 quantize (low byte = rint(x)+128), branch-free 1-store/lane scale write.
#define BM 128
#define BN 128
#define BK 64
#define GM 32   // m-blocks per supergroup; GM*NB = 512 blocks ~ one residency window

__global__ __launch_bounds__(256, 2) void gemm_uv_kernel(
    const unsigned short* __restrict__ xb,
    const unsigned short* __restrict__ w1t,
    const float* __restrict__ b1,
    unsigned char* __restrict__ qUV,      // [M][2048] uint8 (biased +128)
    float* __restrict__ scales,           // [M][32] fp32 (duplicated across 16-row groups)
    int M, int MB)
{
    __shared__ __align__(16) unsigned short smem[16384];   // 32 KB
    unsigned short* sA = smem;
    unsigned short* sB = smem + 8192;

    const int NB = NCOL / BN;   // 16
    int bid = blockIdx.x;
    int g    = bid / (GM * NB);
    int rem  = bid - g * (GM * NB);
    int base = g * GM;
    int gm   = MB - base; if (gm > GM) gm = GM;
    int mb   = base + rem % gm;
    int nb   = rem / gm;
    const int m0 = mb * BM;
    const int n0 = nb * BN;

    const int tid  = threadIdx.x;
    const int wave = tid >> 6;
    const int lane = tid & 63;
    const int q    = lane >> 4;
    const int l15  = lane & 15;
    const int wm   = (wave >> 1) * 64;
    const int wn   = (wave & 1) * 64;

    const int ar = lane >> 3;
    const int ac = ((lane & 7) ^ ar) * 8;       // swizzled staging col-group

    const int swz = l15 & 7;
    const int c0 = (q ^ swz) * 8;               // ks = 0
    const int c1 = ((q ^ swz) ^ 4) * 8;         // ks = 32

    // bias pre-load: acc is seeded with b1 so the epilogue never adds it
    float b1v[4];
    #pragma unroll
    for (int nt = 0; nt < 4; ++nt) {
        int n = n0 + wn + nt * 16 + l15;
        b1v[nt] = (n < D_HID) ? b1[n] : 0.f;
    }

    f32x4 acc[4][4];
    #pragma unroll
    for (int i = 0; i < 4; ++i)
        #pragma unroll
        for (int j = 0; j < 4; ++j)
            acc[i][j] = (f32x4){b1v[j], b1v[j], b1v[j], b1v[j]};

    #pragma unroll 1
    for (int kt = 0; kt < 8; ++kt) {
        const int k0 = kt * BK;
        __syncthreads();
        #pragma unroll
        for (int i = 0; i < 4; ++i) {
            int slot = wave * 4 + i;
            int row  = slot * 8 + ar;
            int m    = m0 + row; if (m >= M) m = M - 1;
            __builtin_amdgcn_global_load_lds(
                (const __attribute__((address_space(1))) void*)(xb + (size_t)m * D_FEAT + k0 + ac),
                (__attribute__((address_space(3))) void*)(sA + slot * 512),
                16, 0, 0);
        }
        #pragma unroll
        for (int i = 0; i < 4; ++i) {
            int slot = wave * 4 + i;
            int row  = slot * 8 + ar;
            __builtin_amdgcn_global_load_lds(
                (const __attribute__((address_space(1))) void*)(w1t + (size_t)(n0 + row) * D_FEAT + k0 + ac),
                (__attribute__((address_space(3))) void*)(sB + slot * 512),
                16, 0, 0);
        }
        __syncthreads();
        {
            short8 a[4], b[4];
            #pragma unroll
            for (int mt = 0; mt < 4; ++mt)
                a[mt] = *(const short8*)(sA + (wm + mt * 16 + l15) * 64 + c0);
            #pragma unroll
            for (int nt = 0; nt < 4; ++nt)
                b[nt] = *(const short8*)(sB + (wn + nt * 16 + l15) * 64 + c0);
            #pragma unroll
            for (int mt = 0; mt < 4; ++mt)
                #pragma unroll
                for (int nt = 0; nt < 4; ++nt)
                    acc[mt][nt] = __builtin_amdgcn_mfma_f32_16x16x32_bf16(a[mt], b[nt], acc[mt][nt], 0, 0, 0);
            #pragma unroll
            for (int mt = 0; mt < 4; ++mt)
                a[mt] = *(const short8*)(sA + (wm + mt * 16 + l15) * 64 + c1);
            #pragma unroll
            for (int nt = 0; nt < 4; ++nt)
                b[nt] = *(const short8*)(sB + (wn + nt * 16 + l15) * 64 + c1);
            #pragma unroll
            for (int mt = 0; mt < 4; ++mt)
                #pragma unroll
                for (int nt = 0; nt < 4; ++nt)
                    acc[mt][nt] = __builtin_amdgcn_mfma_f32_16x16x32_bf16(a[mt], b[nt], acc[mt][nt], 0, 0, 0);
        }
    }

    // ---- epilogue: per-(16-row,64-col) absmax, magic-fmaf uint8 quantize ----
    float msc[4], minv[4];
    #pragma unroll
    for (int mt = 0; mt < 4; ++mt) {
        float m_ = 1e-30f;
        #pragma unroll
        for (int nt = 0; nt < 4; ++nt)
            #pragma unroll
            for (int r = 0; r < 4; ++r)
                m_ = fmaxf(m_, fabsf(acc[mt][nt][r]));
        #pragma unroll
        for (int off = 1; off < 64; off <<= 1)
            m_ = fmaxf(m_, __shfl_xor(m_, off));
        msc[mt]  = m_ * (1.0f / 127.0f);
        minv[mt] = 127.0f * __builtin_amdgcn_rcpf(m_);
    }

    __syncthreads();   // all waves done reading sA/sB
    unsigned char* ep8 = (unsigned char*)smem + wave * 4096;   // wave-private [64][64] u8
    const float MAGIC = 12583040.0f;   // 1.5*2^23 + 128: low byte = rint(x)+128
    #pragma unroll
    for (int mt = 0; mt < 4; ++mt)
        #pragma unroll
        for (int nt = 0; nt < 4; ++nt)
            #pragma unroll
            for (int r = 0; r < 4; ++r) {
                float f = fmaf(acc[mt][nt][r], minv[mt], MAGIC);
                ep8[(mt * 16 + q * 4 + r) * 64 + nt * 16 + l15] =
                    (unsigned char)__builtin_bit_cast(unsigned, f);
            }
    // branch-free scale store: lane (q,l15) covers row group q, row offset l15
    const int chunk = (n0 + wn) >> 6;
    {
        int srow = m0 + wm + q * 16 + l15;
        if (srow < M) scales[(size_t)srow * NCHUNK + chunk] = msc[q];
    }
    // same-wave LDS write->read: wave-private region, no barrier needed
    #pragma unroll
    for (int i = 0; i < 4; ++i) {
        int flat = i * 64 + lane;          // 0..255
        int r   = flat >> 2;               // row 0..63
        int c16 = (flat & 3) * 16;
        int m   = m0 + wm + r;
        if (m < M) {
            int4 v = *(const int4*)(ep8 + r * 64 + c16);
            *(int4*)(qUV + (size_t)m * NCOL + n0 + wn + c16) = v;
        }
    }
}

// ---------- kernel 4: per-edge score = relu(sU*(qU-128) + sV*(qV-128)) . W2 + b2 ----------
__global__ __launch_bounds__(256) void edge_score_kernel(
    const unsigned char* __restrict__ qUV,
    const float* __restrict__ scales,
    const int* __restrict__ src, const int* __restrict__ dst,
    const float* __restrict__ W2, const float* __restrict__ b2,
    float* __restrict__ out, int E)
{
    const int wave = threadIdx.x >> 6;
    const int lane = threadIdx.x & 63;
    const int gw = blockIdx.x * 4 + wave;
    const int e0 = gw * 2;
    const int e1 = e0 + 1;
    if (e0 >= E) return;
    const bool has1 = (e1 < E);

    const int s0 = src[e0];
    const int d0 = dst[e0];
    const int s1 = has1 ? src[e1] : s0;
    const int d1 = has1 ? dst[e1] : d0;

    uint4 qu0 = *(const uint4*)(qUV + (size_t)s0 * NCOL + lane * 16);
    uint4 qv0 = *(const uint4*)(qUV + (size_t)d0 * NCOL + D_HID + lane * 16);
    uint4 qu1 = *(const uint4*)(qUV + (size_t)s1 * NCOL + lane * 16);
    uint4 qv1 = *(const uint4*)(qUV + (size_t)d1 * NCOL + D_HID + lane * 16);
    const int ch = lane >> 2;
    float su0 = scales[(size_t)s0 * NCHUNK + ch];
    float sv0 = scales[(size_t)d0 * NCHUNK + 16 + ch];
    float su1 = scales[(size_t)s1 * NCHUNK + ch];
    float sv1 = scales[(size_t)d1 * NCHUNK + 16 + ch];
    // h = su*(ub-128) + sv*(vb-128) = fmaf(ub,su, fmaf(vb,sv, cc)), cc = -128*(su+sv)
    float cc0 = -128.0f * (su0 + sv0);
    float cc1 = -128.0f * (su1 + sv1);

    const float4* wp = (const float4*)(W2 + lane * 16);
    float4 wa = wp[0], wb = wp[1], wc = wp[2], wd = wp[3];
    float w[16] = {wa.x, wa.y, wa.z, wa.w, wb.x, wb.y, wb.z, wb.w,
                   wc.x, wc.y, wc.z, wc.w, wd.x, wd.y, wd.z, wd.w};
    const float bias = b2[0];

    const unsigned* u0w = (const unsigned*)&qu0; const unsigned* v0w = (const unsigned*)&qv0;
    const unsigned* u1w = (const unsigned*)&qu1; const unsigned* v1w = (const unsigned*)&qv1;

    float acc0 = 0.f, acc1 = 0.f;
    #pragma unroll
    for (int dw = 0; dw < 4; ++dw) {
        #pragma unroll
        for (int b = 0; b < 4; ++b) {
            int k = dw * 4 + b;
            // (float)((w>>8b)&0xFF) -> v_cvt_f32_ubyte[b]
            float ub0 = (float)((u0w[dw] >> (8 * b)) & 0xFFu);
            float vb0 = (float)((v0w[dw] >> (8 * b)) & 0xFFu);
            float h0 = fmaf(ub0, su0, fmaf(vb0, sv0, cc0));
            acc0 = fmaf(fmaxf(h0, 0.f), w[k], acc0);
            float ub1 = (float)((u1w[dw] >> (8 * b)) & 0xFFu);
            float vb1 = (float)((v1w[dw] >> (8 * b)) & 0xFFu);
            float h1 = fmaf(ub1, su1, fmaf(vb1, sv1, cc1));
            acc1 = fmaf(fmaxf(h1, 0.f), w[k], acc1);
        }
    }
    #pragma unroll
    for (int off = 1; off < 64; off <<= 1) {
        acc0 += __shfl_xor(acc0, off);
        acc1 += __shfl_xor(acc1, off);
    }
    if (lane == 0) out[e0] = acc0 + bias;
    if (lane == 1 && has1) out[e1] = acc1 + bias;
}

extern "C" void kernel_launch(void* const* d_in, const int* in_sizes, int n_in,
                              void* d_out, int out_size, void* d_ws, size_t ws_size,
                              hipStream_t stream) {
    const float* x   = (const float*)d_in[0];
    const int*   src = (const int*)d_in[1];
    const int*   dst = (const int*)d_in[2];
    const float* W1  = (const float*)d_in[3];
    const float* b1  = (const float*)d_in[4];
    const float* W2  = (const float*)d_in[5];
    const float* b2  = (const float*)d_in[6];
    float* out = (float*)d_out;

    const int M = in_sizes[0] / D_FEAT;   // 50000 nodes
    const int E = in_sizes[1];            // 200000 edges

    // workspace: qUV u8 [M][2048] | scales f32 [M][32] | xb bf16 [M][512] | w1t bf16 [2048][512]
    char* ws = (char*)d_ws;
    unsigned char*  qUV    = (unsigned char*)ws;
    float*          scales = (float*)(ws + (size_t)M * NCOL);
    unsigned short* xb     = (unsigned short*)(ws + (size_t)M * NCOL + (size_t)M * NCHUNK * 4);
    unsigned short* w1t    = (unsigned short*)(ws + (size_t)M * NCOL + (size_t)M * NCHUNK * 4
                                                  + (size_t)M * D_FEAT * 2);

    const int nx = M * D_FEAT;
    cast_x_kernel<<<(nx / 8 + 255) / 256, 256, 0, stream>>>(x, xb, nx);
    transpose_w1_kernel<<<dim3(32, 16, 2), dim3(32, 8), 0, stream>>>(W1, w1t);
    const int MB = (M + BM - 1) / BM;
    gemm_uv_kernel<<<MB * (NCOL / BN), 256, 0, stream>>>(xb, w1t, b1, qUV, scales, M, MB);
    edge_score_kernel<<<(E + 7) / 8, 256, 0, stream>>>(qUV, scales, src, dst, W2, b2, out, E);
}